// Round 6
// baseline (159.983 us; speedup 1.0000x reference)
//
#include <hip/hip_runtime.h>
#include <stdint.h>

// ContrastiveLoss (SimCLR NT-Xent), B=4096, D=128, T=0.5
// loss = (1/2B) * sum_k log(denom_k)  -  (1/(B*T)) * sum_i dot(z_i, z_j_i)

#define TEMP 0.5f
// exp(x/T) = exp2(x * 2*log2(e)); sqrt(2*log2 e) folded into BOTH stored
// operands so MFMA output is already sim*2*log2(e) (saves a v_mul/element).
#define SCALE_HALF 1.6986435961843206f

typedef __bf16 bf16_t;
typedef bf16_t bf16x8 __attribute__((ext_vector_type(8)));
typedef float floatx4 __attribute__((ext_vector_type(4)));

__device__ __forceinline__ unsigned short f32_to_bf16(float f) {
    union { float f; uint32_t u; } v; v.f = f;
    uint32_t u = v.u;
    uint32_t r = (u + 0x7FFFu + ((u >> 16) & 1u)) >> 16;  // RNE
    return (unsigned short)r;
}

__device__ __forceinline__ bf16x8 as_bf16x8(uint4 v) {
    union { uint4 u; bf16x8 b; } c; c.u = v; return c.b;
}

// ---------------------------------------------------------------------------
// Kernel 1: per-row L2 normalize -> bf16 reps[2B][128] row-major, pre-scaled
// by SCALE_HALF; pos[i] = dot(z_i,z_j) exact fp32 (unscaled). Zeroes rowsum
// and the ticket.
// ---------------------------------------------------------------------------
__global__ __launch_bounds__(256) void norm_pos_kernel(
        const float* __restrict__ p1, const float* __restrict__ p2,
        unsigned short* __restrict__ reps, float* __restrict__ pos,
        float* __restrict__ rowsum, unsigned int* __restrict__ ticket, int B) {
    if (threadIdx.x < 8) rowsum[blockIdx.x * 8 + threadIdx.x] = 0.f;
    if (blockIdx.x == 0 && threadIdx.x == 8) *ticket = 0u;

    int wave = threadIdx.x >> 6;
    int lane = threadIdx.x & 63;
    int i = blockIdx.x * 4 + wave;
    if (i >= B) return;

    const float2* r1 = (const float2*)(p1 + (size_t)i * 128);
    const float2* r2 = (const float2*)(p2 + (size_t)i * 128);
    float2 a = r1[lane];
    float2 b = r2[lane];
    float ss1 = a.x * a.x + a.y * a.y;
    float ss2 = b.x * b.x + b.y * b.y;
    float d   = a.x * b.x + a.y * b.y;
    #pragma unroll
    for (int off = 32; off > 0; off >>= 1) {
        ss1 += __shfl_xor(ss1, off);
        ss2 += __shfl_xor(ss2, off);
        d   += __shfl_xor(d,   off);
    }
    float rn1 = rsqrtf(fmaxf(ss1, 1e-24f));
    float rn2 = rsqrtf(fmaxf(ss2, 1e-24f));
    float s1 = rn1 * SCALE_HALF;
    float s2 = rn2 * SCALE_HALF;

    ushort2* z1 = (ushort2*)reps + (size_t)i * 64;
    ushort2* z2 = (ushort2*)reps + (size_t)(B + i) * 64;
    z1[lane] = make_ushort2(f32_to_bf16(a.x * s1), f32_to_bf16(a.y * s1));
    z2[lane] = make_ushort2(f32_to_bf16(b.x * s2), f32_to_bf16(b.y * s2));

    if (lane == 0) pos[i] = d * rn1 * rn2;
}

// ---------------------------------------------------------------------------
// Kernel 2: sim+exp+rowsum+fused finalize.
// Diagnosis R2/R3/R5: duration ~ total scattered-gather VMEM instrs (each
// B-frag global load = 16x64B segments). Fix: B-strip (256 cols x 256 B =
// 64 KB, CONTIGUOUS in row-major reps) is staged into LDS once per block
// with coalesced loads, stored in FRAGMENT order so inner-loop B-frag reads
// are contiguous 1 KB ds_read_b128 (read bank pattern = conflict floor).
// A stays in registers via one-time gathers (R2-proven). Block = 4 waves x
// 64 rows = 256-row panel x 256-col strip; grid 32x32. Last block (ticket)
// computes the final loss — 2 dispatches total.
// ---------------------------------------------------------------------------
__global__ __launch_bounds__(256) void simexp_kernel(
        const unsigned short* __restrict__ reps, float* __restrict__ rowsum,
        const float* __restrict__ pos, unsigned int* __restrict__ ticket,
        float* __restrict__ out, int nblocks, int B) {
    // frag order: byte addr = ct*4096 + ks*1024 + quad*256 + l16*16
    __shared__ uint4 BsFlat[4096];  // 64 KB
    const int tid  = threadIdx.x;
    const int wave = tid >> 6;
    const int lane = tid & 63;
    const int quad = lane >> 4;
    const int l16  = lane & 15;

    const int rowWave = blockIdx.y * 256 + wave * 64;  // this wave's 64 rows
    const int colBase = blockIdx.x * 256;              // block's 256-col strip
    const uint4* g = (const uint4*)reps;               // 16 uint4 per 256-B row

    // A-fragments: 4 row-tiles x 4 k-steps (64 VGPRs), one-time gathers,
    // issued first so they are in flight during staging.
    bf16x8 a[4][4];
    #pragma unroll
    for (int t = 0; t < 4; ++t)
        #pragma unroll
        for (int ks = 0; ks < 4; ++ks)
            a[t][ks] = as_bf16x8(g[(size_t)(rowWave + t * 16 + l16) * 16 + ks * 4 + quad]);

    // Stage B-strip: iter it covers rows colBase+it*16..+15 (4 KB, coalesced);
    // thread tid's 16-B chunk: row rr = it*16 + (tid>>4), chunk c = tid&15.
    // Frag position: ct = it, ks = c>>2, q = c&3, r16 = tid>>4.
    {
        const int r16 = tid >> 4;
        const int c   = tid & 15;
        const int dst = (c >> 2) * 64 + (c & 3) * 16 + r16;  // + it*256
        const size_t src = (size_t)colBase * 16 + tid;       // + it*256
        #pragma unroll 4
        for (int it = 0; it < 16; ++it)
            BsFlat[it * 256 + dst] = g[src + it * 256];
    }
    __syncthreads();

    float rs[4][4];
    #pragma unroll
    for (int t = 0; t < 4; ++t)
        #pragma unroll
        for (int r = 0; r < 4; ++r) rs[t][r] = 0.f;

    const bool diagBlock = (blockIdx.x == blockIdx.y);

    #pragma unroll 2
    for (int ct = 0; ct < 16; ++ct) {
        // contiguous 1 KB per frag: lane reads BsFlat + ct*256 + ks*64 + lane
        bf16x8 b[4];
        #pragma unroll
        for (int ks = 0; ks < 4; ++ks)
            b[ks] = as_bf16x8(BsFlat[ct * 256 + ks * 64 + lane]);

        floatx4 acc[4];
        #pragma unroll
        for (int t = 0; t < 4; ++t) acc[t] = (floatx4){0.f, 0.f, 0.f, 0.f};

        #pragma unroll
        for (int ks = 0; ks < 4; ++ks)
            #pragma unroll
            for (int t = 0; t < 4; ++t)
                acc[t] = __builtin_amdgcn_mfma_f32_16x16x32_bf16(a[t][ks], b[ks], acc[t], 0, 0, 0);

        if (diagBlock) {
            const int c = colBase + ct * 16 + l16;
            #pragma unroll
            for (int t = 0; t < 4; ++t)
                #pragma unroll
                for (int reg = 0; reg < 4; ++reg) {
                    int r = rowWave + t * 16 + quad * 4 + reg;
                    rs[t][reg] += (r == c) ? 0.f : exp2f(acc[t][reg]);
                }
        } else {
            #pragma unroll
            for (int t = 0; t < 4; ++t)
                #pragma unroll
                for (int reg = 0; reg < 4; ++reg)
                    rs[t][reg] += exp2f(acc[t][reg]);
        }
    }

    // reduce across the 16 columns (l16 lanes) of each quad
    #pragma unroll
    for (int off = 1; off < 16; off <<= 1)
        #pragma unroll
        for (int t = 0; t < 4; ++t)
            #pragma unroll
            for (int reg = 0; reg < 4; ++reg)
                rs[t][reg] += __shfl_xor(rs[t][reg], off);

    if (l16 == 0) {
        #pragma unroll
        for (int t = 0; t < 4; ++t)
            #pragma unroll
            for (int reg = 0; reg < 4; ++reg)
                atomicAdd(&rowsum[rowWave + t * 16 + quad * 4 + reg], rs[t][reg]);
    }

    // --- fused finalize: last block computes the loss ---
    __shared__ int lastFlag;
    __shared__ float wsum[4];
    __threadfence();          // release this block's rowsum atomics
    __syncthreads();
    if (tid == 0) {
        unsigned int t = atomicAdd(ticket, 1u);
        lastFlag = (t == (unsigned int)(nblocks - 1)) ? 1 : 0;
    }
    __syncthreads();
    if (lastFlag) {
        __threadfence();      // acquire
        const int N2 = 2 * B;
        float v = 0.f;
        for (int k = tid; k < N2; k += 256) {
            float r = __hip_atomic_load(&rowsum[k], __ATOMIC_RELAXED,
                                        __HIP_MEMORY_SCOPE_AGENT);
            v += logf(r);
        }
        float p = 0.f;
        for (int i2 = tid; i2 < B; i2 += 256) p += pos[i2];
        float local = v * (1.0f / (float)N2) - p * (1.0f / ((float)B * TEMP));
        #pragma unroll
        for (int off = 32; off > 0; off >>= 1) local += __shfl_xor(local, off);
        if (lane == 0) wsum[wave] = local;
        __syncthreads();
        if (tid == 0) out[0] = wsum[0] + wsum[1] + wsum[2] + wsum[3];
    }
}

extern "C" void kernel_launch(void* const* d_in, const int* in_sizes, int n_in,
                              void* d_out, int out_size, void* d_ws, size_t ws_size,
                              hipStream_t stream) {
    const float* p1 = (const float*)d_in[0];
    const float* p2 = (const float*)d_in[1];
    float* out = (float*)d_out;

    const int B  = in_sizes[0] / 128;   // 4096
    const int N2 = 2 * B;               // 8192

    // ws: [reps bf16: N2*256 B][rowsum: N2*4 B][pos: B*4 B][ticket: 4 B]
    unsigned short* reps = (unsigned short*)d_ws;
    float* rowsum = (float*)((char*)d_ws + (size_t)N2 * 256);
    float* pos    = rowsum + N2;
    unsigned int* ticket = (unsigned int*)(pos + B);

    norm_pos_kernel<<<dim3((B + 3) / 4), dim3(256), 0, stream>>>(
        p1, p2, reps, pos, rowsum, ticket, B);

    dim3 grid(N2 / 256, N2 / 256);  // 32 x 32 = 1024 blocks
    simexp_kernel<<<grid, dim3(256), 0, stream>>>(
        reps, rowsum, pos, ticket, out, grid.x * grid.y, B);
}

// Round 7
// 126.561 us; speedup vs baseline: 1.2641x; 1.2641x over previous
//
#include <hip/hip_runtime.h>
#include <stdint.h>

// ContrastiveLoss (SimCLR NT-Xent), B=4096, D=128, T=0.5
// loss = (1/2B) * sum_k log(denom_k)  -  (1/(B*T)) * sum_i dot(z_i, z_j_i)
// sim = Z Z^T is SYMMETRIC: compute only upper-triangle 256x256 tiles;
// off-diagonal tiles contribute row-sums AND col-sums (transpose tile).

#define TEMP 0.5f
// exp(x/T) = exp2(x * 2*log2 e); sqrt(2*log2 e) folded into BOTH stored bf16
// operands so the MFMA output is already sim*2*log2(e).
#define SCALE_HALF 1.6986435961843206f

typedef __bf16 bf16_t;
typedef bf16_t bf16x8 __attribute__((ext_vector_type(8)));
typedef float floatx4 __attribute__((ext_vector_type(4)));

__device__ __forceinline__ unsigned short f32_to_bf16(float f) {
    union { float f; uint32_t u; } v; v.f = f;
    uint32_t u = v.u;
    uint32_t r = (u + 0x7FFFu + ((u >> 16) & 1u)) >> 16;  // RNE
    return (unsigned short)r;
}

__device__ __forceinline__ bf16x8 as_bf16x8(uint4 v) {
    union { uint4 u; bf16x8 b; } c; c.u = v; return c.b;
}

// ---------------------------------------------------------------------------
// Kernel 1: per-row L2 normalize -> bf16 reps[2B][128] row-major (pre-scaled
// by SCALE_HALF); pos[i] = dot(z_i,z_j) exact fp32. Zeroes rowsum + ticket.
// ---------------------------------------------------------------------------
__global__ __launch_bounds__(256) void norm_pos_kernel(
        const float* __restrict__ p1, const float* __restrict__ p2,
        unsigned short* __restrict__ reps, float* __restrict__ pos,
        float* __restrict__ rowsum, unsigned int* __restrict__ ticket, int B) {
    if (threadIdx.x < 8) rowsum[blockIdx.x * 8 + threadIdx.x] = 0.f;
    if (blockIdx.x == 0 && threadIdx.x == 8) *ticket = 0u;

    int wave = threadIdx.x >> 6;
    int lane = threadIdx.x & 63;
    int i = blockIdx.x * 4 + wave;
    if (i >= B) return;

    const float2* r1 = (const float2*)(p1 + (size_t)i * 128);
    const float2* r2 = (const float2*)(p2 + (size_t)i * 128);
    float2 a = r1[lane];
    float2 b = r2[lane];
    float ss1 = a.x * a.x + a.y * a.y;
    float ss2 = b.x * b.x + b.y * b.y;
    float d   = a.x * b.x + a.y * b.y;
    #pragma unroll
    for (int off = 32; off > 0; off >>= 1) {
        ss1 += __shfl_xor(ss1, off);
        ss2 += __shfl_xor(ss2, off);
        d   += __shfl_xor(d,   off);
    }
    float rn1 = rsqrtf(fmaxf(ss1, 1e-24f));
    float rn2 = rsqrtf(fmaxf(ss2, 1e-24f));
    float s1 = rn1 * SCALE_HALF;
    float s2 = rn2 * SCALE_HALF;

    ushort2* z1 = (ushort2*)reps + (size_t)i * 64;
    ushort2* z2 = (ushort2*)reps + (size_t)(B + i) * 64;
    z1[lane] = make_ushort2(f32_to_bf16(a.x * s1), f32_to_bf16(a.y * s1));
    z2[lane] = make_ushort2(f32_to_bf16(b.x * s2), f32_to_bf16(b.y * s2));

    if (lane == 0) pos[i] = d * rn1 * rn2;
}

// ---------------------------------------------------------------------------
// Kernel 2: symmetric sim+exp+rowsum, R2's proven structure (row-major reps,
// register A-frags, global B-gathers, no LDS staging). Grid 32x32 but only
// upper-triangle blocks (bx >= by) compute: 528 active, 496 skip straight to
// the ticket. Off-diag blocks emit col-sums too (2 shuffles + 1 atomic per
// ctile). Fused finalize via FENCE-FREE ticket: __syncthreads() drains
// vmcnt(0) per wave (atomics complete at the coherence point) — no
// __threadfence(), which on 8-XCD gfx950 emits per-wave L2 writeback-
// invalidates and cost R4/R6 ~50 us.
// ---------------------------------------------------------------------------
__global__ __launch_bounds__(256) void simexp_kernel(
        const unsigned short* __restrict__ reps, float* __restrict__ rowsum,
        const float* __restrict__ pos, unsigned int* __restrict__ ticket,
        float* __restrict__ out, int nblocks, int B) {
    const int tid  = threadIdx.x;
    const int wave = tid >> 6;
    const int lane = tid & 63;
    const int quad = lane >> 4;
    const int l16  = lane & 15;
    const int bx = blockIdx.x, by = blockIdx.y;

    if (bx >= by) {  // upper-triangle block: do the tile
        const int rowWave = by * 256 + wave * 64;  // this wave's 64 rows
        const int colBase = bx * 256;              // block's 256-col strip
        const uint4* g = (const uint4*)reps;       // 16 uint4 per 256-B row

        // A-fragments: 4 row-tiles x 4 k-steps (64 VGPRs), one-time gathers
        bf16x8 a[4][4];
        #pragma unroll
        for (int t = 0; t < 4; ++t)
            #pragma unroll
            for (int ks = 0; ks < 4; ++ks)
                a[t][ks] = as_bf16x8(g[(size_t)(rowWave + t * 16 + l16) * 16 + ks * 4 + quad]);

        float rs[4][4];
        #pragma unroll
        for (int t = 0; t < 4; ++t)
            #pragma unroll
            for (int r = 0; r < 4; ++r) rs[t][r] = 0.f;

        const bool diag = (bx == by);

        #pragma unroll 2
        for (int ct = 0; ct < 16; ++ct) {
            const int colT = colBase + ct * 16;
            bf16x8 b[4];
            #pragma unroll
            for (int ks = 0; ks < 4; ++ks)
                b[ks] = as_bf16x8(g[(size_t)(colT + l16) * 16 + ks * 4 + quad]);

            floatx4 acc[4];
            #pragma unroll
            for (int t = 0; t < 4; ++t) acc[t] = (floatx4){0.f, 0.f, 0.f, 0.f};

            #pragma unroll
            for (int ks = 0; ks < 4; ++ks)
                #pragma unroll
                for (int t = 0; t < 4; ++t)
                    acc[t] = __builtin_amdgcn_mfma_f32_16x16x32_bf16(a[t][ks], b[ks], acc[t], 0, 0, 0);

            if (diag) {
                const int c = colT + l16;
                #pragma unroll
                for (int t = 0; t < 4; ++t)
                    #pragma unroll
                    for (int reg = 0; reg < 4; ++reg) {
                        int r = rowWave + t * 16 + quad * 4 + reg;
                        rs[t][reg] += (r == c) ? 0.f : exp2f(acc[t][reg]);
                    }
            } else {
                float cs = 0.f;  // this lane's 16-row partial of column colT+l16
                #pragma unroll
                for (int t = 0; t < 4; ++t)
                    #pragma unroll
                    for (int reg = 0; reg < 4; ++reg) {
                        float e = exp2f(acc[t][reg]);
                        rs[t][reg] += e;
                        cs += e;
                    }
                // reduce over quads (rows): lanes sharing l16
                cs += __shfl_xor(cs, 16);
                cs += __shfl_xor(cs, 32);
                if (quad == 0)  // full 64-row col sum -> mirrored row
                    atomicAdd(&rowsum[colT + l16], cs);
            }
        }

        // row sums: reduce across the 16 columns (l16 lanes) of each quad
        #pragma unroll
        for (int off = 1; off < 16; off <<= 1)
            #pragma unroll
            for (int t = 0; t < 4; ++t)
                #pragma unroll
                for (int reg = 0; reg < 4; ++reg)
                    rs[t][reg] += __shfl_xor(rs[t][reg], off);

        if (l16 == 0) {
            #pragma unroll
            for (int t = 0; t < 4; ++t)
                #pragma unroll
                for (int reg = 0; reg < 4; ++reg)
                    atomicAdd(&rowsum[rowWave + t * 16 + quad * 4 + reg], rs[t][reg]);
        }
    }

    // --- fence-free fused finalize ---
    __shared__ unsigned int lastFlag;
    __shared__ float wsum[4];
    // ensure THIS wave's atomics are complete at the coherence point
    asm volatile("s_waitcnt vmcnt(0)" ::: "memory");
    __syncthreads();  // all 4 waves drained (barrier implies vmcnt(0) anyway)
    if (tid == 0) {
        unsigned int t = __hip_atomic_fetch_add(ticket, 1u, __ATOMIC_RELAXED,
                                                __HIP_MEMORY_SCOPE_AGENT);
        lastFlag = (t == (unsigned int)(nblocks - 1)) ? 1u : 0u;
    }
    __syncthreads();
    if (lastFlag) {
        const int N2 = 2 * B;
        float v = 0.f;
        for (int k = tid; k < N2; k += 256) {
            float r = __hip_atomic_load(&rowsum[k], __ATOMIC_RELAXED,
                                        __HIP_MEMORY_SCOPE_AGENT);
            v += logf(r);
        }
        float p = 0.f;
        for (int i2 = tid; i2 < B; i2 += 256) p += pos[i2];
        float local = v * (1.0f / (float)N2) - p * (1.0f / ((float)B * TEMP));
        #pragma unroll
        for (int off = 32; off > 0; off >>= 1) local += __shfl_xor(local, off);
        if (lane == 0) wsum[wave] = local;
        __syncthreads();
        if (tid == 0) out[0] = wsum[0] + wsum[1] + wsum[2] + wsum[3];
    }
}

extern "C" void kernel_launch(void* const* d_in, const int* in_sizes, int n_in,
                              void* d_out, int out_size, void* d_ws, size_t ws_size,
                              hipStream_t stream) {
    const float* p1 = (const float*)d_in[0];
    const float* p2 = (const float*)d_in[1];
    float* out = (float*)d_out;

    const int B  = in_sizes[0] / 128;   // 4096
    const int N2 = 2 * B;               // 8192

    // ws: [reps bf16: N2*256 B][rowsum: N2*4 B][pos: B*4 B][ticket: 4 B]
    unsigned short* reps = (unsigned short*)d_ws;
    float* rowsum = (float*)((char*)d_ws + (size_t)N2 * 256);
    float* pos    = rowsum + N2;
    unsigned int* ticket = (unsigned int*)(pos + B);

    norm_pos_kernel<<<dim3((B + 3) / 4), dim3(256), 0, stream>>>(
        p1, p2, reps, pos, rowsum, ticket, B);

    dim3 grid(N2 / 256, N2 / 256);  // 32x32; lower-triangle blocks skip to ticket
    simexp_kernel<<<grid, dim3(256), 0, stream>>>(
        reps, rowsum, pos, ticket, out, grid.x * grid.y, B);
}